// Round 9
// baseline (435.779 us; speedup 1.0000x reference)
//
#include <hip/hip_runtime.h>

// P2G quadratic B-spline scatter, MI355X — v8: native ds_add_f32 in K2.
//
// v7 established: K1 ~76 us (scattered-transaction floor ~26 G/s), total
// 182 us, leaving ~106 us in K2+K3+overhead. v5's fixed-point K2 pays
// ~5-8 VALU ops per f32->u64 convert x 54/particle (~30-40 us/CU VALU) and
// u64 LDS atomics hit 2 banks/lane. v8 uses HIP unsafeAtomicAdd on LDS
// floats -> native ds_add_f32 (the safe fp atomicAdd CAS-loop measured at
// ~215 cyc/instr in R4 is bypassed): no converts, 1 bank/lane, 8KB LDS.
// Numerics: plain fp32 accumulation, same as passing v1/v3 (absmax 3.9e-3).
//   K1: bin particles; slot = atomicAdd(cnt[bin]); slots[bin*CAP+slot] =
//       {clipped px,py,pz, prob}
//   K2: one workgroup per bin; coalesced slot reads; 27 taps x 2
//       ds_add_f32 into 10^3 LDS float tiles; float2 tile store.
//   K3: per cell, fp32-sum the 1..8 covering tiles, out = wp/(w+1e-7).
// Fallback (ws too small): v1 interleaved global-atomic path.

namespace {

constexpr int   G        = 64;
constexpr int   G3       = G * G * G;            // 262144
constexpr int   BIN      = 8;                    // cells per bin per axis
constexpr int   NBX      = G / BIN;              // 8 bins per axis
constexpr int   BINS_PB  = NBX * NBX * NBX;      // 512 bins per batch
constexpr int   TILE     = BIN + 2;              // 10 (halo -1..8)
constexpr int   TILE3    = TILE * TILE * TILE;   // 1000
constexpr int   CAP      = 512;                  // slots per bin (avg ~244)
constexpr float EPS_CLIP = 1e-5f;
constexpr float EPS_DIV  = 1e-7f;
constexpr float INV_DX   = 64.0f;                // 1/DX (exact pow2)

__device__ __forceinline__ float clip01(float v) {
    return fminf(fmaxf(v, EPS_CLIP), 1.0f - EPS_CLIP);
}

__device__ __forceinline__ void bspline_w(float f, float* w) {
    w[0] = 0.5f * (1.0f - f) * (1.0f - f);
    w[1] = 0.75f - (f - 0.5f) * (f - 0.5f);
    w[2] = 0.5f * f * f;
}

// ---------------- K1: bin particles, materialize clipped payload ----------

__global__ void bin_particles_mat(const float* __restrict__ pos,
                                  const float* __restrict__ prob,
                                  const int*   __restrict__ bidx,
                                  int*         __restrict__ cnt,    // nbins
                                  float4*      __restrict__ slots,  // nbins*CAP
                                  int L) {
    int i = blockIdx.x * blockDim.x + threadIdx.x;
    if (i >= L) return;
    float px = clip01(pos[3 * i + 0]);
    float py = clip01(pos[3 * i + 1]);
    float pz = clip01(pos[3 * i + 2]);
    int bx = (int)(px * INV_DX);
    int by = (int)(py * INV_DX);
    int bz = (int)(pz * INV_DX);
    int bin = ((bidx[i] * NBX + (bx >> 3)) * NBX + (by >> 3)) * NBX + (bz >> 3);
    int slot = atomicAdd(&cnt[bin], 1);
    if (slot < CAP) slots[(size_t)bin * CAP + slot] = make_float4(px, py, pz, prob[i]);
}

// ---------------- K2: per-bin LDS tile accumulation (ds_add_f32) ----------

__global__ void __launch_bounds__(256)
accumulate_bins(const float4* __restrict__ slots,
                const int*    __restrict__ cnt,
                float2*       __restrict__ tiles) {   // nbins*TILE3
    __shared__ float t_w[TILE3];
    __shared__ float t_wp[TILE3];
    const int bin = blockIdx.x;
    const int tid = threadIdx.x;

    for (int j = tid; j < TILE3; j += 256) { t_w[j] = 0.f; t_wp[j] = 0.f; }
    __syncthreads();

    const int n = min(cnt[bin], CAP);
    // bin origin in cells (bin = ((b*8+bbx)*8+bby)*8+bbz)
    const int bx0 = ((bin >> 6) & 7) * BIN;
    const int by0 = ((bin >> 3) & 7) * BIN;
    const int bz0 = (bin & 7) * BIN;
    const float4* sbase = slots + (size_t)bin * CAP;

    for (int s = tid; s < n; s += 256) {
        float4 r = sbase[s];                         // coalesced 16B load
        float xp = r.x * INV_DX;                     // pos pre-clipped in K1
        float yp = r.y * INV_DX;
        float zp = r.z * INV_DX;
        int bx = (int)xp, by = (int)yp, bz = (int)zp;
        float wx[3], wy[3], wz[3];
        bspline_w(xp - (float)bx, wx);
        bspline_w(yp - (float)by, wy);
        bspline_w(zp - (float)bz, wz);
        float p = r.w;
        // local base, pre-offset so tap index = l0 + a directly in [0, 9]
        int l0x = bx - bx0, l0y = by - by0, l0z = bz - bz0;
#pragma unroll
        for (int a = 0; a < 3; ++a) {
            int ix = (l0x + a) * TILE;
#pragma unroll
            for (int c = 0; c < 3; ++c) {
                int ixy = (ix + l0y + c) * TILE;
                float wxy = wx[a] * wy[c];
#pragma unroll
                for (int e = 0; e < 3; ++e) {
                    float w  = wxy * wz[e];
                    int   ci = ixy + l0z + e;
                    unsafeAtomicAdd(&t_w[ci],  w);     // native ds_add_f32
                    unsafeAtomicAdd(&t_wp[ci], w * p);
                }
            }
        }
    }
    __syncthreads();

    float2* gt = tiles + (size_t)bin * TILE3;
    for (int j = tid; j < TILE3; j += 256) {
        gt[j] = make_float2(t_w[j], t_wp[j]);
    }
}

// ---------------- K3: gather overlapping tiles + divide -------------------

__global__ void finalize_tiles(const float2* __restrict__ tiles,
                               float*        __restrict__ out,
                               int total) {
    int c = blockIdx.x * blockDim.x + threadIdx.x;
    if (c >= total) return;
    int cz = c & 63, cy = (c >> 6) & 63, cx = (c >> 12) & 63, b = c >> 18;
    int bx = cx >> 3, mx = cx & 7;
    int by = cy >> 3, my = cy & 7;
    int bz = cz >> 3, mz = cz & 7;

    // per-axis list of (bin coord, tile-local index) covering this cell
    int xb[2], xl[2], nx = 1; xb[0] = bx; xl[0] = mx + 1;
    if (mx == 0 && bx > 0)       { xb[1] = bx - 1; xl[1] = 9; nx = 2; }
    else if (mx == 7 && bx < 7)  { xb[1] = bx + 1; xl[1] = 0; nx = 2; }
    int yb[2], yl[2], ny = 1; yb[0] = by; yl[0] = my + 1;
    if (my == 0 && by > 0)       { yb[1] = by - 1; yl[1] = 9; ny = 2; }
    else if (my == 7 && by < 7)  { yb[1] = by + 1; yl[1] = 0; ny = 2; }
    int zb[2], zl[2], nz = 1; zb[0] = bz; zl[0] = mz + 1;
    if (mz == 0 && bz > 0)       { zb[1] = bz - 1; zl[1] = 9; nz = 2; }
    else if (mz == 7 && bz < 7)  { zb[1] = bz + 1; zl[1] = 0; nz = 2; }

    float w = 0.f, wp = 0.f;
    for (int i = 0; i < nx; ++i)
        for (int j = 0; j < ny; ++j)
            for (int k = 0; k < nz; ++k) {
                int bin = ((b * NBX + xb[i]) * NBX + yb[j]) * NBX + zb[k];
                float2 v = tiles[(size_t)bin * TILE3
                                 + (xl[i] * TILE + yl[j]) * TILE + zl[k]];
                w += v.x; wp += v.y;
            }
    out[c] = wp / (w + EPS_DIV);
}

// ---------------- fallback kernels (v1) -----------------------------------

__global__ void scatter_interleaved(const float* __restrict__ pos,
                                    const float* __restrict__ prob,
                                    const int*   __restrict__ bidx,
                                    float2*      __restrict__ grid,
                                    int L) {
    int i = blockIdx.x * blockDim.x + threadIdx.x;
    if (i >= L) return;
    float xp = clip01(pos[3 * i + 0]) * INV_DX;
    float yp = clip01(pos[3 * i + 1]) * INV_DX;
    float zp = clip01(pos[3 * i + 2]) * INV_DX;
    int bx = (int)xp, by = (int)yp, bz = (int)zp;
    float wx[3], wy[3], wz[3];
    bspline_w(xp - (float)bx, wx);
    bspline_w(yp - (float)by, wy);
    bspline_w(zp - (float)bz, wz);
    float p = prob[i];
    float2* gbase = grid + (size_t)bidx[i] * G3;
#pragma unroll
    for (int a = 0; a < 3; ++a) {
        int tx = bx + a - 1;
        if (tx < 0 || tx >= G) continue;
#pragma unroll
        for (int c = 0; c < 3; ++c) {
            int ty = by + c - 1;
            if (ty < 0 || ty >= G) continue;
            float wxy = wx[a] * wy[c];
            int rowoff = (tx * G + ty) * G;
#pragma unroll
            for (int e = 0; e < 3; ++e) {
                int tz = bz + e - 1;
                if (tz < 0 || tz >= G) continue;
                float w = wxy * wz[e];
                float2* cell = gbase + rowoff + tz;
                atomicAdd(&cell->x, w);
                atomicAdd(&cell->y, w * p);
            }
        }
    }
}

__global__ void finalize_interleaved(const float2* __restrict__ grid,
                                     float* __restrict__ out, int n) {
    int i = blockIdx.x * blockDim.x + threadIdx.x;
    if (i >= n) return;
    float2 c = grid[i];
    out[i] = c.y / (c.x + EPS_DIV);
}

} // anonymous namespace

extern "C" void kernel_launch(void* const* d_in, const int* in_sizes, int n_in,
                              void* d_out, int out_size, void* d_ws, size_t ws_size,
                              hipStream_t stream) {
    const float* pos  = (const float*)d_in[0];
    const float* prob = (const float*)d_in[1];
    const int*   bidx = (const int*)d_in[2];
    float* out = (float*)d_out;

    const int L = in_sizes[1];            // prob has L elements
    const int B = out_size / G3;          // out_size == B * G3
    const int nbins = B * BINS_PB;

    const int threads = 256;
    const int pblocks = (L + threads - 1) / threads;
    const int fblocks = (out_size + threads - 1) / threads;

    // ws layout: [tiles: nbins*TILE3*8B][slots: nbins*CAP*16B][cnt: nbins*4B]
    const size_t tiles_bytes = (size_t)nbins * TILE3 * sizeof(float2);
    const size_t slots_bytes = (size_t)nbins * CAP * sizeof(float4);
    const size_t cnt_bytes   = (size_t)nbins * sizeof(int);
    const size_t need        = tiles_bytes + slots_bytes + cnt_bytes;

    if (ws_size >= need) {
        float2* tiles = (float2*)d_ws;
        float4* slots = (float4*)((char*)d_ws + tiles_bytes);
        int*    cnt   = (int*)((char*)d_ws + tiles_bytes + slots_bytes);

        hipMemsetAsync(cnt, 0, cnt_bytes, stream);
        bin_particles_mat<<<pblocks, threads, 0, stream>>>(pos, prob, bidx,
                                                           cnt, slots, L);
        accumulate_bins<<<nbins, threads, 0, stream>>>(slots, cnt, tiles);
        finalize_tiles<<<fblocks, threads, 0, stream>>>(tiles, out, out_size);
    } else if (ws_size >= (size_t)out_size * 2 * sizeof(float)) {
        // v1 fallback: interleaved global-atomic scatter
        float2* grid = (float2*)d_ws;
        hipMemsetAsync(d_ws, 0, (size_t)out_size * 2 * sizeof(float), stream);
        scatter_interleaved<<<pblocks, threads, 0, stream>>>(pos, prob, bidx, grid, L);
        finalize_interleaved<<<fblocks, threads, 0, stream>>>(grid, out, out_size);
    }
}

// Round 10
// 181.955 us; speedup vs baseline: 2.3950x; 2.3950x over previous
//
#include <hip/hip_runtime.h>

// P2G quadratic B-spline scatter, MI355X — v9: v7 (u64 LDS fixed-point) +
// FXS-hoisted weights in K2.
//
// v8 post-mortem: unsafeAtomicAdd on LDS floats does NOT emit ds_add_f32 on
// gfx950/ROCm7.2 — K2 returned to the 287us CAS-loop timing (same as v3).
// Fact: fp32 LDS atomics are ~215cyc CAS loops regardless of unsafe flags;
// integer LDS atomics are native. v5/v7's u64 fixed-point K2 (<40us) is the
// only fast LDS accumulation. Structure (all counter-verified):
//   K1 ~76us = 2M scattered transactions @ measured ~26 G-op/s chip wall
//   K2 ~35-40us = 844K ds_add_u64 + f32->u64 convert VALU
//   K3 ~25-30us = 32MB tile gather + divide;  +~15us memset/graph overhead
//   K1: bin particles; slot = atomicAdd(cnt[bin]); slots[bin*CAP+slot] =
//       {clipped px,py,pz, prob}
//   K2: one workgroup per bin; coalesced slot reads; 27 taps x 2 native
//       ds_add_u64 (2^42 fixed point, scale hoisted into wx) into 10^3
//       LDS tiles; float2 tile store.
//   K3: per cell, fp32-sum the 1..8 covering tiles, out = wp/(w+1e-7).
// Fallback (ws too small): v1 interleaved global-atomic path.

namespace {

constexpr int   G        = 64;
constexpr int   G3       = G * G * G;            // 262144
constexpr int   BIN      = 8;                    // cells per bin per axis
constexpr int   NBX      = G / BIN;              // 8 bins per axis
constexpr int   BINS_PB  = NBX * NBX * NBX;      // 512 bins per batch
constexpr int   TILE     = BIN + 2;              // 10 (halo -1..8)
constexpr int   TILE3    = TILE * TILE * TILE;   // 1000
constexpr int   CAP      = 512;                  // slots per bin (avg ~244)
constexpr float EPS_CLIP = 1e-5f;
constexpr float EPS_DIV  = 1e-7f;
constexpr float INV_DX   = 64.0f;                // 1/DX (exact pow2)
constexpr float FXS      = 4398046511104.0f;     // 2^42 fixed-point scale
constexpr float INV_FXS  = 1.0f / FXS;           // 2^-42

__device__ __forceinline__ float clip01(float v) {
    return fminf(fmaxf(v, EPS_CLIP), 1.0f - EPS_CLIP);
}

__device__ __forceinline__ void bspline_w(float f, float* w) {
    w[0] = 0.5f * (1.0f - f) * (1.0f - f);
    w[1] = 0.75f - (f - 0.5f) * (f - 0.5f);
    w[2] = 0.5f * f * f;
}

// ---------------- K1: bin particles, materialize clipped payload ----------

__global__ void bin_particles_mat(const float* __restrict__ pos,
                                  const float* __restrict__ prob,
                                  const int*   __restrict__ bidx,
                                  int*         __restrict__ cnt,    // nbins
                                  float4*      __restrict__ slots,  // nbins*CAP
                                  int L) {
    int i = blockIdx.x * blockDim.x + threadIdx.x;
    if (i >= L) return;
    float px = clip01(pos[3 * i + 0]);
    float py = clip01(pos[3 * i + 1]);
    float pz = clip01(pos[3 * i + 2]);
    int bx = (int)(px * INV_DX);
    int by = (int)(py * INV_DX);
    int bz = (int)(pz * INV_DX);
    int bin = ((bidx[i] * NBX + (bx >> 3)) * NBX + (by >> 3)) * NBX + (bz >> 3);
    int slot = atomicAdd(&cnt[bin], 1);
    if (slot < CAP) slots[(size_t)bin * CAP + slot] = make_float4(px, py, pz, prob[i]);
}

// ---------------- K2: per-bin LDS tile accumulation (2x ds_add_u64) -------

__global__ void __launch_bounds__(256)
accumulate_bins(const float4* __restrict__ slots,
                const int*    __restrict__ cnt,
                float2*       __restrict__ tiles) {   // nbins*TILE3
    __shared__ unsigned long long t_w[TILE3];
    __shared__ unsigned long long t_wp[TILE3];
    const int bin = blockIdx.x;
    const int tid = threadIdx.x;

    for (int j = tid; j < TILE3; j += 256) { t_w[j] = 0ull; t_wp[j] = 0ull; }
    __syncthreads();

    const int n = min(cnt[bin], CAP);
    // bin origin in cells (bin = ((b*8+bbx)*8+bby)*8+bbz)
    const int bx0 = ((bin >> 6) & 7) * BIN;
    const int by0 = ((bin >> 3) & 7) * BIN;
    const int bz0 = (bin & 7) * BIN;
    const float4* sbase = slots + (size_t)bin * CAP;

    for (int s = tid; s < n; s += 256) {
        float4 r = sbase[s];                         // coalesced 16B load
        float xp = r.x * INV_DX;                     // pos pre-clipped in K1
        float yp = r.y * INV_DX;
        float zp = r.z * INV_DX;
        int bx = (int)xp, by = (int)yp, bz = (int)zp;
        float wx[3], wy[3], wz[3];
        bspline_w(xp - (float)bx, wx);
        bspline_w(yp - (float)by, wy);
        bspline_w(zp - (float)bz, wz);
        float p = r.w;
        // hoist the fixed-point scale into the x-weights: one mul per axis
        // tap instead of two muls per 3D tap (fp32 relative rounding keeps
        // the v5 small-w accuracy analysis intact)
        wx[0] *= FXS; wx[1] *= FXS; wx[2] *= FXS;
        // local base, pre-offset so tap index = l0 + a directly in [0, 9]
        int l0x = bx - bx0, l0y = by - by0, l0z = bz - bz0;
#pragma unroll
        for (int a = 0; a < 3; ++a) {
            int ix = (l0x + a) * TILE;
#pragma unroll
            for (int c = 0; c < 3; ++c) {
                int ixy = (ix + l0y + c) * TILE;
                float wxyS = wx[a] * wy[c];
#pragma unroll
                for (int e = 0; e < 3; ++e) {
                    float wS  = wxyS * wz[e];        // = w * 2^42
                    int   ci  = ixy + l0z + e;
                    atomicAdd(&t_w[ci],  (unsigned long long)wS);
                    atomicAdd(&t_wp[ci], (unsigned long long)(wS * p));
                }
            }
        }
    }
    __syncthreads();

    float2* gt = tiles + (size_t)bin * TILE3;
    for (int j = tid; j < TILE3; j += 256) {
        gt[j] = make_float2((float)t_w[j] * INV_FXS, (float)t_wp[j] * INV_FXS);
    }
}

// ---------------- K3: gather overlapping tiles + divide -------------------

__global__ void finalize_tiles(const float2* __restrict__ tiles,
                               float*        __restrict__ out,
                               int total) {
    int c = blockIdx.x * blockDim.x + threadIdx.x;
    if (c >= total) return;
    int cz = c & 63, cy = (c >> 6) & 63, cx = (c >> 12) & 63, b = c >> 18;
    int bx = cx >> 3, mx = cx & 7;
    int by = cy >> 3, my = cy & 7;
    int bz = cz >> 3, mz = cz & 7;

    // per-axis list of (bin coord, tile-local index) covering this cell
    int xb[2], xl[2], nx = 1; xb[0] = bx; xl[0] = mx + 1;
    if (mx == 0 && bx > 0)       { xb[1] = bx - 1; xl[1] = 9; nx = 2; }
    else if (mx == 7 && bx < 7)  { xb[1] = bx + 1; xl[1] = 0; nx = 2; }
    int yb[2], yl[2], ny = 1; yb[0] = by; yl[0] = my + 1;
    if (my == 0 && by > 0)       { yb[1] = by - 1; yl[1] = 9; ny = 2; }
    else if (my == 7 && by < 7)  { yb[1] = by + 1; yl[1] = 0; ny = 2; }
    int zb[2], zl[2], nz = 1; zb[0] = bz; zl[0] = mz + 1;
    if (mz == 0 && bz > 0)       { zb[1] = bz - 1; zl[1] = 9; nz = 2; }
    else if (mz == 7 && bz < 7)  { zb[1] = bz + 1; zl[1] = 0; nz = 2; }

    float w = 0.f, wp = 0.f;
    for (int i = 0; i < nx; ++i)
        for (int j = 0; j < ny; ++j)
            for (int k = 0; k < nz; ++k) {
                int bin = ((b * NBX + xb[i]) * NBX + yb[j]) * NBX + zb[k];
                float2 v = tiles[(size_t)bin * TILE3
                                 + (xl[i] * TILE + yl[j]) * TILE + zl[k]];
                w += v.x; wp += v.y;
            }
    out[c] = wp / (w + EPS_DIV);
}

// ---------------- fallback kernels (v1) -----------------------------------

__global__ void scatter_interleaved(const float* __restrict__ pos,
                                    const float* __restrict__ prob,
                                    const int*   __restrict__ bidx,
                                    float2*      __restrict__ grid,
                                    int L) {
    int i = blockIdx.x * blockDim.x + threadIdx.x;
    if (i >= L) return;
    float xp = clip01(pos[3 * i + 0]) * INV_DX;
    float yp = clip01(pos[3 * i + 1]) * INV_DX;
    float zp = clip01(pos[3 * i + 2]) * INV_DX;
    int bx = (int)xp, by = (int)yp, bz = (int)zp;
    float wx[3], wy[3], wz[3];
    bspline_w(xp - (float)bx, wx);
    bspline_w(yp - (float)by, wy);
    bspline_w(zp - (float)bz, wz);
    float p = prob[i];
    float2* gbase = grid + (size_t)bidx[i] * G3;
#pragma unroll
    for (int a = 0; a < 3; ++a) {
        int tx = bx + a - 1;
        if (tx < 0 || tx >= G) continue;
#pragma unroll
        for (int c = 0; c < 3; ++c) {
            int ty = by + c - 1;
            if (ty < 0 || ty >= G) continue;
            float wxy = wx[a] * wy[c];
            int rowoff = (tx * G + ty) * G;
#pragma unroll
            for (int e = 0; e < 3; ++e) {
                int tz = bz + e - 1;
                if (tz < 0 || tz >= G) continue;
                float w = wxy * wz[e];
                float2* cell = gbase + rowoff + tz;
                atomicAdd(&cell->x, w);
                atomicAdd(&cell->y, w * p);
            }
        }
    }
}

__global__ void finalize_interleaved(const float2* __restrict__ grid,
                                     float* __restrict__ out, int n) {
    int i = blockIdx.x * blockDim.x + threadIdx.x;
    if (i >= n) return;
    float2 c = grid[i];
    out[i] = c.y / (c.x + EPS_DIV);
}

} // anonymous namespace

extern "C" void kernel_launch(void* const* d_in, const int* in_sizes, int n_in,
                              void* d_out, int out_size, void* d_ws, size_t ws_size,
                              hipStream_t stream) {
    const float* pos  = (const float*)d_in[0];
    const float* prob = (const float*)d_in[1];
    const int*   bidx = (const int*)d_in[2];
    float* out = (float*)d_out;

    const int L = in_sizes[1];            // prob has L elements
    const int B = out_size / G3;          // out_size == B * G3
    const int nbins = B * BINS_PB;

    const int threads = 256;
    const int pblocks = (L + threads - 1) / threads;
    const int fblocks = (out_size + threads - 1) / threads;

    // ws layout: [tiles: nbins*TILE3*8B][slots: nbins*CAP*16B][cnt: nbins*4B]
    const size_t tiles_bytes = (size_t)nbins * TILE3 * sizeof(float2);
    const size_t slots_bytes = (size_t)nbins * CAP * sizeof(float4);
    const size_t cnt_bytes   = (size_t)nbins * sizeof(int);
    const size_t need        = tiles_bytes + slots_bytes + cnt_bytes;

    if (ws_size >= need) {
        float2* tiles = (float2*)d_ws;
        float4* slots = (float4*)((char*)d_ws + tiles_bytes);
        int*    cnt   = (int*)((char*)d_ws + tiles_bytes + slots_bytes);

        hipMemsetAsync(cnt, 0, cnt_bytes, stream);
        bin_particles_mat<<<pblocks, threads, 0, stream>>>(pos, prob, bidx,
                                                           cnt, slots, L);
        accumulate_bins<<<nbins, threads, 0, stream>>>(slots, cnt, tiles);
        finalize_tiles<<<fblocks, threads, 0, stream>>>(tiles, out, out_size);
    } else if (ws_size >= (size_t)out_size * 2 * sizeof(float)) {
        // v1 fallback: interleaved global-atomic scatter
        float2* grid = (float2*)d_ws;
        hipMemsetAsync(d_ws, 0, (size_t)out_size * 2 * sizeof(float), stream);
        scatter_interleaved<<<pblocks, threads, 0, stream>>>(pos, prob, bidx, grid, L);
        finalize_interleaved<<<fblocks, threads, 0, stream>>>(grid, out, out_size);
    }
}